// Round 14
// baseline (165.204 us; speedup 1.0000x reference)
//
#include <hip/hip_runtime.h>

using bf16x8 = __attribute__((ext_vector_type(8))) short;
using f32x4  = __attribute__((ext_vector_type(4))) float;
using f32x16 = __attribute__((ext_vector_type(16))) float;
using u32x2  = __attribute__((ext_vector_type(2))) unsigned int;
using u32x4  = __attribute__((ext_vector_type(4))) unsigned int;

__device__ __forceinline__ unsigned short f2bf(float f) {
  unsigned int u = __float_as_uint(f);
  u = u + 0x7fffu + ((u >> 16) & 1u);   // round-to-nearest-even
  return (unsigned short)(u >> 16);
}

#if __has_builtin(__builtin_amdgcn_exp2f)
#define EXP2(x) __builtin_amdgcn_exp2f(x)
#else
#define EXP2(x) __expf((x) * 0.69314718056f)
#endif

// v_cvt_pk_bf16_f32: pack 2 f32 -> 2 bf16 (RTNE) in one instruction [T12]
__device__ __forceinline__ unsigned int cvt_pk_bf16(float lo, float hi) {
  unsigned int r;
  asm("v_cvt_pk_bf16_f32 %0, %1, %2" : "=v"(r) : "v"(lo), "v"(hi));
  return r;
}

#define GLL16(SRC, DST) __builtin_amdgcn_global_load_lds( \
    (const __attribute__((address_space(1))) unsigned int*)(SRC), \
    (__attribute__((address_space(3))) unsigned int*)(DST), 16, 0, 0)

// ---------------- merged converts (single launch) ----------------
__global__ __launch_bounds__(256) void cvt_all_kernel(
    const float* __restrict__ x, unsigned short* __restrict__ xb,
    const float* __restrict__ Wq, const float* __restrict__ Wk,
    const float* __restrict__ Wv, const float* __restrict__ Wo,
    unsigned short* __restrict__ wqkvt, unsigned short* __restrict__ wot) {
  __shared__ float tile[32][33];
  const int bx = blockIdx.x;
  if (bx < 8192) {
    const int i = bx * 256 + threadIdx.x;
    const float4 v = reinterpret_cast<const float4*>(x)[i];
    ushort2 o0 = { f2bf(v.x), f2bf(v.y) };
    ushort2 o1 = { f2bf(v.z), f2bf(v.w) };
    reinterpret_cast<ushort2*>(xb)[2 * i]     = o0;
    reinterpret_cast<ushort2*>(xb)[2 * i + 1] = o1;
    return;
  }
  const float* W; unsigned short* Wt; int N, bi;
  if (bx < 9216)      { W = Wq; Wt = wqkvt;                        N = 1024; bi = bx - 8192; }
  else if (bx < 9280) { W = Wk; Wt = wqkvt + (size_t)1024 * 1024;  N = 64;   bi = bx - 9216; }
  else if (bx < 9344) { W = Wv; Wt = wqkvt + (size_t)1088 * 1024;  N = 64;   bi = bx - 9280; }
  else                { W = Wo; Wt = wot;                          N = 1024; bi = bx - 9344; }
  const int nb = N >> 5;
  const int n0 = (bi % nb) * 32, k0 = (bi / nb) * 32;
  const int tx = threadIdx.x & 31, ty = threadIdx.x >> 5;
  #pragma unroll
  for (int i = 0; i < 32; i += 8)
    tile[ty + i][tx] = W[(size_t)(k0 + ty + i) * N + n0 + tx];
  __syncthreads();
  #pragma unroll
  for (int i = 0; i < 32; i += 8)
    Wt[(size_t)(n0 + ty + i) * 1024 + k0 + tx] = f2bf(tile[tx][ty + i]);
}

// ---------------- GEMM (m97 structure): C = A(M x K) @ Bt^T + bias ----------------
// MODE 0: fused QKV. N=1152. col<1024 -> Q bf16 (b,h,n,d) scaled by 0.125*log2e;
//         col in [1024,1088) -> K (b*n,64); col >= 1088 -> V^T (b,d,n) with the
//         key index bit2<->bit3 swapped within each 16-group (PV positional layout).
// MODE 2: out0 = fp32 row-major (M x N).
template<int MODE>
__global__ __launch_bounds__(256) void gemm_kernel(
    const unsigned short* __restrict__ A, const unsigned short* __restrict__ Bt,
    const float* __restrict__ bias0, const float* __restrict__ bias1,
    const float* __restrict__ bias2,
    void* __restrict__ out0, void* __restrict__ out1, void* __restrict__ out2,
    int K, int N) {
  __shared__ __align__(16) unsigned short alds[2][128 * 32];
  __shared__ __align__(16) unsigned short blds[2][128 * 32];

  const int t    = threadIdx.x;
  const int lane = t & 63;
  const int wid  = t >> 6;
  const int lr = lane & 15, lg = lane >> 4;
  const int row0 = blockIdx.x * 128;
  const int col0 = blockIdx.y * 128;

  const size_t ldb = (size_t)K * 2;
  const char* Ag = (const char*)A  + (size_t)(row0 + (t >> 2)) * ldb + ((t & 3) << 4);
  const char* Bg = (const char*)Bt + (size_t)(col0 + (t >> 2)) * ldb + ((t & 3) << 4);
  char* adst = (char*)alds[0] + wid * 1024;
  char* bdst = (char*)blds[0] + wid * 1024;

  auto stage = [&](int buf, int k0) {
    const size_t kb = (size_t)k0 * 2;
    #pragma unroll
    for (int c = 0; c < 2; ++c) {
      GLL16(Ag + (size_t)c * 64 * ldb + kb, adst + buf * 8192 + c * 4096);
      GLL16(Bg + (size_t)c * 64 * ldb + kb, bdst + buf * 8192 + c * 4096);
    }
  };

  f32x4 acc[4][4];
  #pragma unroll
  for (int i = 0; i < 4; ++i)
    #pragma unroll
    for (int j = 0; j < 4; ++j)
      #pragma unroll
      for (int r = 0; r < 4; ++r) acc[i][j][r] = 0.f;

  stage(0, 0);
  __syncthreads();

  for (int step = 0; step < 32; ++step) {
    const int cur = step & 1;
    if (step < 31) stage(cur ^ 1, (step + 1) * 32);

    const char* ab = (const char*)alds[cur] + (wid >> 1) * 4096;
    const char* bb = (const char*)blds[cur] + (wid & 1) * 4096;
    bf16x8 am[4], bn[4];
    #pragma unroll
    for (int i = 0; i < 4; ++i)
      am[i] = *reinterpret_cast<const bf16x8*>(ab + (i * 16 + lr) * 64 + lg * 16);
    #pragma unroll
    for (int j = 0; j < 4; ++j)
      bn[j] = *reinterpret_cast<const bf16x8*>(bb + (j * 16 + lr) * 64 + lg * 16);
    #pragma unroll
    for (int i = 0; i < 4; ++i)
      #pragma unroll
      for (int j = 0; j < 4; ++j)
        acc[i][j] = __builtin_amdgcn_mfma_f32_16x16x32_bf16(am[i], bn[j], acc[i][j], 0, 0, 0);

    __syncthreads();
  }

  const int wrow0 = row0 + (wid >> 1) * 64;
  const int wcol0 = col0 + (wid & 1) * 64;
  #pragma unroll
  for (int i = 0; i < 4; ++i) {
    #pragma unroll
    for (int j = 0; j < 4; ++j) {
      const int col = wcol0 + j * 16 + lr;
      float bias;
      if constexpr (MODE == 0)
        bias = (col < 1024) ? bias0[col] : ((col < 1088) ? bias1[col - 1024] : bias2[col - 1088]);
      else
        bias = bias0[col];
      #pragma unroll
      for (int r = 0; r < 4; ++r) {
        const int row = wrow0 + i * 16 + lg * 4 + r;
        float v = acc[i][j][r] + bias;
        if constexpr (MODE == 0) {
          const int b = row >> 11, n = row & 2047;
          if (col < 1024) {
            v *= 0.180336880111f;  // 0.125 * log2(e): softmax scale + exp2 domain
            const int h = col >> 6, d = col & 63;
            ((unsigned short*)out0)[(((b * 16 + h) * 2048) + n) * 64 + d] = f2bf(v);
          } else if (col < 1088) {
            ((unsigned short*)out1)[row * 64 + (col - 1024)] = f2bf(v);      // K: (b*2048+n, d)
          } else {
            const int np = (n & ~15) | (n & 3) | ((n & 4) << 1) | ((n & 8) >> 1);
            ((unsigned short*)out2)[(b * 64 + (col - 1088)) * 2048 + np] = f2bf(v);
          }
        } else {
          ((float*)out0)[(size_t)row * N + col] = v;
        }
      }
    }
  }
}

// ---------------- attention (R13 base + SGB-pinned 2-deep pipeline + zacc) ---------
// 8 waves x 32 q-rows, grid (8, 64). KVBLK=128 (4 chunks of 32 keys per period).
// K LDS [128][64d] / V LDS [64d][128] dbuf via global_load_lds, XOR chunk swizzles.
// Pipeline: sc=QK(0); for ct: {sn=QK(ct+1) and Exp(sc) with a sched_group_barrier
// interleave directive (4 x {1 DS_READ, 1 MFMA, 12 ALU}) so next-chunk MFMAs feed the
// matrix pipe while exp runs; then PV(ct)}. zacc: first QK MFMA uses a never-written
// zero C -> deletes the per-chunk f32x16 zero-init movs. Math identical to verified
// rounds 7/8/10/13: swapped+positional QK, S^T D-layout col=q=la /
// row=key=(r&3)+8*(r>>2)+4*hi, in-register P -> PV B-frag, bit2<->bit3-permuted V,
// no max subtraction (scores pre-scaled 0.125*log2e), lsum reduced in epilogue.
__global__ __launch_bounds__(512, 2) void attn_kernel(
    const unsigned short* __restrict__ Q,   // (bh, n, 64), pre-scaled by 0.125*log2e
    const unsigned short* __restrict__ Kb,  // (b, n, 64)
    const unsigned short* __restrict__ Vt,  // (b, 64, n-permuted)
    unsigned short* __restrict__ Ao) {      // (b, n, 1024)
  __shared__ __align__(16) unsigned short klds[2][128 * 64];  // 16 KB / buf
  __shared__ __align__(16) unsigned short vlds[2][64 * 128];  // 16 KB / buf

  const int lane = threadIdx.x & 63;
  const int wid  = threadIdx.x >> 6;
  const int la = lane & 31, hi = lane >> 5;
  const int swz = (la & 7) << 4;            // read swizzle (row&7 == la&7 for all reads)
  const int bh = blockIdx.y, b = bh >> 4, h = bh & 15;
  const int q0 = blockIdx.x * 256 + wid * 32;

  const unsigned short* Qb = Q + (size_t)bh * 2048 * 64;
  const char* Kbase = (const char*)(Kb + (size_t)b * 2048 * 64);
  const char* Vbase = (const char*)(Vt + (size_t)b * 64 * 2048);

  // K staging: wave stages key-rows wid*16 + g*8 + (lane>>3), chunk (lane&7)^(row&7)
  const int srowK  = lane >> 3;                       // 0..7
  const int schnkK = (lane & 7) ^ srowK;              // row&7 == srowK for both g
  const int koff0 = (wid * 16 + 0 + srowK) * 128 + schnkK * 16;
  const int koff1 = (wid * 16 + 8 + srowK) * 128 + schnkK * 16;
  // V staging: wave stages d-rows wid*8 + g*4 + (lane>>4), 256B rows, 16 chunks
  const int srowV = lane >> 4;                        // 0..3
  const int voff0 = (wid * 8 + 0 + srowV) * 4096 + ((lane & 15) ^ ((0 + srowV) & 7)) * 16;
  const int voff1 = (wid * 8 + 4 + srowV) * 4096 + ((lane & 15) ^ ((4 + srowV) & 7)) * 16;
  char* kB = (char*)klds[0] + wid * 2048;             // wave-uniform dst bases
  char* vB = (char*)vlds[0] + wid * 2048;

  auto stage = [&](int buf, int p) {                  // p = 128-key period index
    const size_t kgb = (size_t)p * 16384;             // 128 keys * 128 B
    const size_t vgb = (size_t)p * 256;               // 128 keys * 2 B
    GLL16(Kbase + kgb + koff0, kB + buf * 16384);
    GLL16(Kbase + kgb + koff1, kB + buf * 16384 + 1024);
    GLL16(Vbase + vgb + voff0, vB + buf * 16384);
    GLL16(Vbase + vgb + voff1, vB + buf * 16384 + 1024);
  };

  // Q B-frags (loop-invariant), positional: col=q=q0+la, d = kc*16 + hi*8 + j
  bf16x8 qa[4];
  #pragma unroll
  for (int kc = 0; kc < 4; ++kc)
    qa[kc] = *reinterpret_cast<const bf16x8*>(&Qb[(q0 + la) * 64 + kc * 16 + hi * 8]);

  // never-written zero accumulator: first QK MFMA reads it as C (saves 16 movs/chunk)
  f32x16 zacc;
  #pragma unroll
  for (int r = 0; r < 16; ++r) zacc[r] = 0.f;

  float lsum = 0.f;
  f32x16 o[2];
  #pragma unroll
  for (int dt = 0; dt < 2; ++dt)
    #pragma unroll
    for (int r = 0; r < 16; ++r) o[dt][r] = 0.f;

  stage(0, 0);
  __syncthreads();

  for (int p = 0; p < 16; ++p) {
    const int cur = p & 1;
    if (p < 15) stage(cur ^ 1, p + 1);   // prefetch next 128-key pair

    const char* kb8 = (const char*)klds[cur];
    const char* vb8 = (const char*)vlds[cur];

    // QK of one 32-key chunk (positional A/B, enumeration cancels); C-in = zacc
    auto QKc = [&](int ct) -> f32x16 {
      bf16x8 kf[4];
      #pragma unroll
      for (int kc = 0; kc < 4; ++kc)
        kf[kc] = *reinterpret_cast<const bf16x8*>(
            kb8 + ((ct * 32 + la) << 7) + ((((kc << 1) + hi) << 4) ^ swz));
      f32x16 s = __builtin_amdgcn_mfma_f32_32x32x16_bf16(kf[0], qa[0], zacc, 0, 0, 0);
      #pragma unroll
      for (int kc = 1; kc < 4; ++kc)
        s = __builtin_amdgcn_mfma_f32_32x32x16_bf16(kf[kc], qa[kc], s, 0, 0, 0);
      return s;
    };

    // exp + pack of one S-tile
    auto EXPP = [&](const f32x16& s, unsigned int (&W)[4][2]) {
      float ps = 0.f;
      #pragma unroll
      for (int r2 = 0; r2 < 4; ++r2) {
        const float p0 = EXP2(s[r2 * 4 + 0]);
        const float p1 = EXP2(s[r2 * 4 + 1]);
        const float p2 = EXP2(s[r2 * 4 + 2]);
        const float p3 = EXP2(s[r2 * 4 + 3]);
        ps += (p0 + p1) + (p2 + p3);
        W[r2][0] = cvt_pk_bf16(p0, p1);
        W[r2][1] = cvt_pk_bf16(p2, p3);
      }
      lsum += ps;
    };

    // PV of one chunk from its packed P words
    auto PV = [&](int ct, const unsigned int (&W)[4][2]) {
      __builtin_amdgcn_s_setprio(1);
      #pragma unroll
      for (int ks = 0; ks < 2; ++ks) {
        u32x4 pwv;
        pwv[0] = W[2 * ks][0];
        pwv[1] = W[2 * ks][1];
        pwv[2] = W[2 * ks + 1][0];
        pwv[3] = W[2 * ks + 1][1];
        const bf16x8 pb = __builtin_bit_cast(bf16x8, pwv);
        #pragma unroll
        for (int dt = 0; dt < 2; ++dt) {
          const bf16x8 vf = *reinterpret_cast<const bf16x8*>(
              vb8 + ((dt * 32 + la) << 8) + (((((ct * 2 + ks) << 1) + hi) << 4) ^ swz));
          o[dt] = __builtin_amdgcn_mfma_f32_32x32x16_bf16(vf, pb, o[dt], 0, 0, 0);
        }
      }
      __builtin_amdgcn_s_setprio(0);
    };

    // 2-deep pipeline with sched_group_barrier interleave of QK(ct+1) with Exp(ct)
    f32x16 sc = QKc(0);
    #pragma unroll
    for (int ct = 0; ct < 4; ++ct) {
      unsigned int W[4][2];
      if (ct < 3) {
        f32x16 sn = QKc(ct + 1);
        EXPP(sc, W);
        // directive: emit 4 x {1 ds_read, 1 MFMA, 12 ALU} -> next-chunk MFMAs
        // interleaved with this chunk's exp/pack (feeds matrix pipe during exp)
        #pragma unroll
        for (int i = 0; i < 4; ++i) {
          __builtin_amdgcn_sched_group_barrier(0x100, 1, 0);  // DS_READ
          __builtin_amdgcn_sched_group_barrier(0x008, 1, 0);  // MFMA
          __builtin_amdgcn_sched_group_barrier(0x001, 12, 0); // ALU (incl trans)
        }
        PV(ct, W);
        sc = sn;
      } else {
        EXPP(sc, W);
        PV(3, W);
      }
    }

    __syncthreads();   // staged period p+1 visible; everyone done with buf[cur]
  }

  // epilogue: one cross-half reduce, normalize, packed 8B stores.
  // D layout (32x32): row = d = dt*32 + (r&3) + 8*(r>>2) + 4*hi, col = q = la.
  lsum += __shfl_xor(lsum, 32);
  const float inv = 1.f / lsum;
  const size_t rowoff = (size_t)(b * 2048 + q0 + la) * 1024 + h * 64 + hi * 4;
  #pragma unroll
  for (int dt = 0; dt < 2; ++dt) {
    #pragma unroll
    for (int r2 = 0; r2 < 4; ++r2) {
      u32x2 w;
      w[0] = cvt_pk_bf16(o[dt][r2 * 4 + 0] * inv, o[dt][r2 * 4 + 1] * inv);
      w[1] = cvt_pk_bf16(o[dt][r2 * 4 + 2] * inv, o[dt][r2 * 4 + 3] * inv);
      *(u32x2*)(Ao + rowoff + dt * 32 + r2 * 8) = w;
    }
  }
}

// ---------------- launch ----------------
extern "C" void kernel_launch(void* const* d_in, const int* in_sizes, int n_in,
                              void* d_out, int out_size, void* d_ws, size_t ws_size,
                              hipStream_t stream) {
  const float* x  = (const float*)d_in[0];
  const float* Wq = (const float*)d_in[1];
  const float* bq = (const float*)d_in[2];
  const float* Wk = (const float*)d_in[3];
  const float* bk = (const float*)d_in[4];
  const float* Wv = (const float*)d_in[5];
  const float* bv = (const float*)d_in[6];
  const float* Wo = (const float*)d_in[7];
  const float* bo = (const float*)d_in[8];
  float* out = (float*)d_out;

  char* ws = (char*)d_ws;
  size_t off = 0;
  auto alloc = [&](size_t bytes) -> void* {
    void* p = ws + off;
    off += (bytes + 255) & ~(size_t)255;
    return p;
  };
  unsigned short* xb    = (unsigned short*)alloc((size_t)8192 * 1024 * 2); // x bf16
  unsigned short* wqkvt = (unsigned short*)alloc((size_t)1152 * 1024 * 2); // [Wq;Wk;Wv]^T bf16
  unsigned short* wot   = (unsigned short*)alloc((size_t)1024 * 1024 * 2); // Wo^T bf16
  unsigned short* qb    = (unsigned short*)alloc((size_t)8192 * 1024 * 2); // Q (b,h,n,d) scaled
  unsigned short* kb    = (unsigned short*)alloc((size_t)8192 * 64 * 2);   // K (b,n,d)
  unsigned short* vt    = (unsigned short*)alloc((size_t)4 * 64 * 2048 * 2); // V^T permuted
  unsigned short* ao    = (unsigned short*)alloc((size_t)8192 * 1024 * 2); // attn out (b,n,1024)

  cvt_all_kernel<<<10368, 256, 0, stream>>>(x, xb, Wq, Wk, Wv, Wo, wqkvt, wot);
  gemm_kernel<0><<<dim3(64, 9), 256, 0, stream>>>(xb, wqkvt, bq, bk, bv, qb, kb, vt, 1024, 1152);
  attn_kernel<<<dim3(8, 64), 512, 0, stream>>>(qb, kb, vt, ao);
  gemm_kernel<2><<<dim3(64, 8), 256, 0, stream>>>(ao, wot, bo, nullptr, nullptr, out, nullptr, nullptr, 1024, 1024);
}

// Round 15
// 151.623 us; speedup vs baseline: 1.0896x; 1.0896x over previous
//
#include <hip/hip_runtime.h>

using bf16x8 = __attribute__((ext_vector_type(8))) short;
using f32x4  = __attribute__((ext_vector_type(4))) float;
using f32x16 = __attribute__((ext_vector_type(16))) float;
using u32x2  = __attribute__((ext_vector_type(2))) unsigned int;
using u32x4  = __attribute__((ext_vector_type(4))) unsigned int;

__device__ __forceinline__ unsigned short f2bf(float f) {
  unsigned int u = __float_as_uint(f);
  u = u + 0x7fffu + ((u >> 16) & 1u);   // round-to-nearest-even
  return (unsigned short)(u >> 16);
}

#if __has_builtin(__builtin_amdgcn_exp2f)
#define EXP2(x) __builtin_amdgcn_exp2f(x)
#else
#define EXP2(x) __expf((x) * 0.69314718056f)
#endif

// v_cvt_pk_bf16_f32: pack 2 f32 -> 2 bf16 (RTNE) in one instruction [T12]
__device__ __forceinline__ unsigned int cvt_pk_bf16(float lo, float hi) {
  unsigned int r;
  asm("v_cvt_pk_bf16_f32 %0, %1, %2" : "=v"(r) : "v"(lo), "v"(hi));
  return r;
}

#define GLL16(SRC, DST) __builtin_amdgcn_global_load_lds( \
    (const __attribute__((address_space(1))) unsigned int*)(SRC), \
    (__attribute__((address_space(3))) unsigned int*)(DST), 16, 0, 0)

// ---------------- merged converts (single launch) ----------------
__global__ __launch_bounds__(256) void cvt_all_kernel(
    const float* __restrict__ x, unsigned short* __restrict__ xb,
    const float* __restrict__ Wq, const float* __restrict__ Wk,
    const float* __restrict__ Wv, const float* __restrict__ Wo,
    unsigned short* __restrict__ wqkvt, unsigned short* __restrict__ wot) {
  __shared__ float tile[32][33];
  const int bx = blockIdx.x;
  if (bx < 8192) {
    const int i = bx * 256 + threadIdx.x;
    const float4 v = reinterpret_cast<const float4*>(x)[i];
    ushort2 o0 = { f2bf(v.x), f2bf(v.y) };
    ushort2 o1 = { f2bf(v.z), f2bf(v.w) };
    reinterpret_cast<ushort2*>(xb)[2 * i]     = o0;
    reinterpret_cast<ushort2*>(xb)[2 * i + 1] = o1;
    return;
  }
  const float* W; unsigned short* Wt; int N, bi;
  if (bx < 9216)      { W = Wq; Wt = wqkvt;                        N = 1024; bi = bx - 8192; }
  else if (bx < 9280) { W = Wk; Wt = wqkvt + (size_t)1024 * 1024;  N = 64;   bi = bx - 9216; }
  else if (bx < 9344) { W = Wv; Wt = wqkvt + (size_t)1088 * 1024;  N = 64;   bi = bx - 9280; }
  else                { W = Wo; Wt = wot;                          N = 1024; bi = bx - 9344; }
  const int nb = N >> 5;
  const int n0 = (bi % nb) * 32, k0 = (bi / nb) * 32;
  const int tx = threadIdx.x & 31, ty = threadIdx.x >> 5;
  #pragma unroll
  for (int i = 0; i < 32; i += 8)
    tile[ty + i][tx] = W[(size_t)(k0 + ty + i) * N + n0 + tx];
  __syncthreads();
  #pragma unroll
  for (int i = 0; i < 32; i += 8)
    Wt[(size_t)(n0 + ty + i) * 1024 + k0 + tx] = f2bf(tile[tx][ty + i]);
}

// ---------------- GEMM (m97 structure): C = A(M x K) @ Bt^T + bias ----------------
// MODE 0: fused QKV. N=1152. col<1024 -> Q bf16 (b,h,n,d) scaled by 0.125*log2e;
//         col in [1024,1088) -> K (b*n,64); col >= 1088 -> V^T (b,d,n) with the
//         key index bit2<->bit3 swapped within each 16-group (PV positional layout).
// MODE 2: out0 = fp32 row-major (M x N).
// NOTE: default block->XCD round-robin already co-locates A-tile sharers
// ((bx + 64*by) % 8 == bx % 8, constant across by) -> no swizzle here.
template<int MODE>
__global__ __launch_bounds__(256) void gemm_kernel(
    const unsigned short* __restrict__ A, const unsigned short* __restrict__ Bt,
    const float* __restrict__ bias0, const float* __restrict__ bias1,
    const float* __restrict__ bias2,
    void* __restrict__ out0, void* __restrict__ out1, void* __restrict__ out2,
    int K, int N) {
  __shared__ __align__(16) unsigned short alds[2][128 * 32];
  __shared__ __align__(16) unsigned short blds[2][128 * 32];

  const int t    = threadIdx.x;
  const int lane = t & 63;
  const int wid  = t >> 6;
  const int lr = lane & 15, lg = lane >> 4;
  const int row0 = blockIdx.x * 128;
  const int col0 = blockIdx.y * 128;

  const size_t ldb = (size_t)K * 2;
  const char* Ag = (const char*)A  + (size_t)(row0 + (t >> 2)) * ldb + ((t & 3) << 4);
  const char* Bg = (const char*)Bt + (size_t)(col0 + (t >> 2)) * ldb + ((t & 3) << 4);
  char* adst = (char*)alds[0] + wid * 1024;
  char* bdst = (char*)blds[0] + wid * 1024;

  auto stage = [&](int buf, int k0) {
    const size_t kb = (size_t)k0 * 2;
    #pragma unroll
    for (int c = 0; c < 2; ++c) {
      GLL16(Ag + (size_t)c * 64 * ldb + kb, adst + buf * 8192 + c * 4096);
      GLL16(Bg + (size_t)c * 64 * ldb + kb, bdst + buf * 8192 + c * 4096);
    }
  };

  f32x4 acc[4][4];
  #pragma unroll
  for (int i = 0; i < 4; ++i)
    #pragma unroll
    for (int j = 0; j < 4; ++j)
      #pragma unroll
      for (int r = 0; r < 4; ++r) acc[i][j][r] = 0.f;

  stage(0, 0);
  __syncthreads();

  for (int step = 0; step < 32; ++step) {
    const int cur = step & 1;
    if (step < 31) stage(cur ^ 1, (step + 1) * 32);

    const char* ab = (const char*)alds[cur] + (wid >> 1) * 4096;
    const char* bb = (const char*)blds[cur] + (wid & 1) * 4096;
    bf16x8 am[4], bn[4];
    #pragma unroll
    for (int i = 0; i < 4; ++i)
      am[i] = *reinterpret_cast<const bf16x8*>(ab + (i * 16 + lr) * 64 + lg * 16);
    #pragma unroll
    for (int j = 0; j < 4; ++j)
      bn[j] = *reinterpret_cast<const bf16x8*>(bb + (j * 16 + lr) * 64 + lg * 16);
    #pragma unroll
    for (int i = 0; i < 4; ++i)
      #pragma unroll
      for (int j = 0; j < 4; ++j)
        acc[i][j] = __builtin_amdgcn_mfma_f32_16x16x32_bf16(am[i], bn[j], acc[i][j], 0, 0, 0);

    __syncthreads();
  }

  const int wrow0 = row0 + (wid >> 1) * 64;
  const int wcol0 = col0 + (wid & 1) * 64;
  #pragma unroll
  for (int i = 0; i < 4; ++i) {
    #pragma unroll
    for (int j = 0; j < 4; ++j) {
      const int col = wcol0 + j * 16 + lr;
      float bias;
      if constexpr (MODE == 0)
        bias = (col < 1024) ? bias0[col] : ((col < 1088) ? bias1[col - 1024] : bias2[col - 1088]);
      else
        bias = bias0[col];
      #pragma unroll
      for (int r = 0; r < 4; ++r) {
        const int row = wrow0 + i * 16 + lg * 4 + r;
        float v = acc[i][j][r] + bias;
        if constexpr (MODE == 0) {
          const int b = row >> 11, n = row & 2047;
          if (col < 1024) {
            v *= 0.180336880111f;  // 0.125 * log2(e): softmax scale + exp2 domain
            const int h = col >> 6, d = col & 63;
            ((unsigned short*)out0)[(((b * 16 + h) * 2048) + n) * 64 + d] = f2bf(v);
          } else if (col < 1088) {
            ((unsigned short*)out1)[row * 64 + (col - 1024)] = f2bf(v);      // K: (b*2048+n, d)
          } else {
            const int np = (n & ~15) | (n & 3) | ((n & 4) << 1) | ((n & 8) >> 1);
            ((unsigned short*)out2)[(b * 64 + (col - 1088)) * 2048 + np] = f2bf(v);
          }
        } else {
          ((float*)out0)[(size_t)row * N + col] = v;
        }
      }
    }
  }
}

// ---------------- attention (R13-exact + bh-XCD co-location remap) ----------------
// 8 waves x 32 q-rows, grid (8, 64) = 512 blocks. KVBLK=128 (4 chunks of 32 keys per
// period, 16 periods). K LDS [128][64d] / V LDS [64d][128] dbuf via global_load_lds
// with verified XOR chunk swizzles. Math identical to verified rounds 7/8/10/13:
// swapped+positional QK (cancellation-safe), S^T D-layout col=q=la /
// row=key=(r&3)+8*(r>>2)+4*hi, in-register P -> PV B-frag, bit2<->bit3-permuted V,
// no max subtraction (scores pre-scaled 0.125*log2e), lsum reduced in epilogue.
// ROUND 15: bijective block remap f=(bx+8*by): bh=(f%8)*8+(f/8)%8, qt=f/64 —
// co-locates all 8 q-tile blocks of a bh group (and one batch's 512 KB KV) on one
// XCD under round-robin dispatch -> global_load_lds sources become L2-hot.
__global__ __launch_bounds__(512, 2) void attn_kernel(
    const unsigned short* __restrict__ Q,   // (bh, n, 64), pre-scaled by 0.125*log2e
    const unsigned short* __restrict__ Kb,  // (b, n, 64)
    const unsigned short* __restrict__ Vt,  // (b, 64, n-permuted)
    unsigned short* __restrict__ Ao) {      // (b, n, 1024)
  __shared__ __align__(16) unsigned short klds[2][128 * 64];  // 16 KB / buf
  __shared__ __align__(16) unsigned short vlds[2][64 * 128];  // 16 KB / buf

  const int lane = threadIdx.x & 63;
  const int wid  = threadIdx.x >> 6;
  const int la = lane & 31, hi = lane >> 5;
  const int swz = (la & 7) << 4;            // read swizzle (row&7 == la&7 for all reads)

  // bh-XCD co-location remap (bijective): same-bh blocks land on one XCD
  const int f  = blockIdx.x + 8 * blockIdx.y;     // hardware dispatch-order index
  const int bh = (f & 7) * 8 + ((f >> 3) & 7);    // 0..63
  const int qt = f >> 6;                          // 0..7
  const int b = bh >> 4, h = bh & 15;
  const int q0 = qt * 256 + wid * 32;

  const unsigned short* Qb = Q + (size_t)bh * 2048 * 64;
  const char* Kbase = (const char*)(Kb + (size_t)b * 2048 * 64);
  const char* Vbase = (const char*)(Vt + (size_t)b * 64 * 2048);

  // K staging: wave stages key-rows wid*16 + g*8 + (lane>>3), chunk (lane&7)^(row&7)
  const int srowK  = lane >> 3;                       // 0..7
  const int schnkK = (lane & 7) ^ srowK;              // row&7 == srowK for both g
  const int koff0 = (wid * 16 + 0 + srowK) * 128 + schnkK * 16;
  const int koff1 = (wid * 16 + 8 + srowK) * 128 + schnkK * 16;
  // V staging: wave stages d-rows wid*8 + g*4 + (lane>>4), 256B rows, 16 chunks
  const int srowV = lane >> 4;                        // 0..3
  const int voff0 = (wid * 8 + 0 + srowV) * 4096 + ((lane & 15) ^ ((0 + srowV) & 7)) * 16;
  const int voff1 = (wid * 8 + 4 + srowV) * 4096 + ((lane & 15) ^ ((4 + srowV) & 7)) * 16;
  char* kB = (char*)klds[0] + wid * 2048;             // wave-uniform dst bases
  char* vB = (char*)vlds[0] + wid * 2048;

  auto stage = [&](int buf, int p) {                  // p = 128-key period index
    const size_t kgb = (size_t)p * 16384;             // 128 keys * 128 B
    const size_t vgb = (size_t)p * 256;               // 128 keys * 2 B
    GLL16(Kbase + kgb + koff0, kB + buf * 16384);
    GLL16(Kbase + kgb + koff1, kB + buf * 16384 + 1024);
    GLL16(Vbase + vgb + voff0, vB + buf * 16384);
    GLL16(Vbase + vgb + voff1, vB + buf * 16384 + 1024);
  };

  // Q B-frags (loop-invariant), positional: col=q=q0+la, d = kc*16 + hi*8 + j
  bf16x8 qa[4];
  #pragma unroll
  for (int kc = 0; kc < 4; ++kc)
    qa[kc] = *reinterpret_cast<const bf16x8*>(&Qb[(q0 + la) * 64 + kc * 16 + hi * 8]);

  float lsum = 0.f;
  f32x16 o[2];
  #pragma unroll
  for (int dt = 0; dt < 2; ++dt)
    #pragma unroll
    for (int r = 0; r < 16; ++r) o[dt][r] = 0.f;

  stage(0, 0);
  __syncthreads();

  for (int p = 0; p < 16; ++p) {
    const int cur = p & 1;
    if (p < 15) stage(cur ^ 1, p + 1);   // prefetch next 128-key pair

    const char* kb8 = (const char*)klds[cur];
    const char* vb8 = (const char*)vlds[cur];

    // QK of one 32-key chunk (positional A/B, enumeration cancels)
    auto QKc = [&](int ct) -> f32x16 {
      f32x16 s;
      #pragma unroll
      for (int r = 0; r < 16; ++r) s[r] = 0.f;
      __builtin_amdgcn_s_setprio(1);
      #pragma unroll
      for (int kc = 0; kc < 4; ++kc) {
        const bf16x8 kf = *reinterpret_cast<const bf16x8*>(
            kb8 + ((ct * 32 + la) << 7) + ((((kc << 1) + hi) << 4) ^ swz));
        s = __builtin_amdgcn_mfma_f32_32x32x16_bf16(kf, qa[kc], s, 0, 0, 0);
      }
      __builtin_amdgcn_s_setprio(0);
      return s;
    };

    // exp + pack + PV of one 32-key chunk from its S-tile
    auto ExpPV = [&](int ct, const f32x16& s) {
      unsigned int W[4][2];
      float ps = 0.f;
      #pragma unroll
      for (int r2 = 0; r2 < 4; ++r2) {
        const float p0 = EXP2(s[r2 * 4 + 0]);
        const float p1 = EXP2(s[r2 * 4 + 1]);
        const float p2 = EXP2(s[r2 * 4 + 2]);
        const float p3 = EXP2(s[r2 * 4 + 3]);
        ps += (p0 + p1) + (p2 + p3);
        W[r2][0] = cvt_pk_bf16(p0, p1);
        W[r2][1] = cvt_pk_bf16(p2, p3);
      }
      lsum += ps;
      __builtin_amdgcn_s_setprio(1);
      #pragma unroll
      for (int ks = 0; ks < 2; ++ks) {
        u32x4 pwv;
        pwv[0] = W[2 * ks][0];
        pwv[1] = W[2 * ks][1];
        pwv[2] = W[2 * ks + 1][0];
        pwv[3] = W[2 * ks + 1][1];
        const bf16x8 pb = __builtin_bit_cast(bf16x8, pwv);
        #pragma unroll
        for (int dt = 0; dt < 2; ++dt) {
          const bf16x8 vf = *reinterpret_cast<const bf16x8*>(
              vb8 + ((dt * 32 + la) << 8) + (((((ct * 2 + ks) << 1) + hi) << 4) ^ swz));
          o[dt] = __builtin_amdgcn_mfma_f32_32x32x16_bf16(vf, pb, o[dt], 0, 0, 0);
        }
      }
      __builtin_amdgcn_s_setprio(0);
    };

    // static 2-state pipeline over the 4 independent chunks
    f32x16 s0 = QKc(0);
    f32x16 s1 = QKc(1);
    ExpPV(0, s0);
    s0 = QKc(2);
    ExpPV(1, s1);
    s1 = QKc(3);
    ExpPV(2, s0);
    ExpPV(3, s1);

    __syncthreads();   // staged period p+1 visible; everyone done with buf[cur]
  }

  // epilogue: one cross-half reduce, normalize, packed 8B stores.
  // D layout (32x32): row = d = dt*32 + (r&3) + 8*(r>>2) + 4*hi, col = q = la.
  lsum += __shfl_xor(lsum, 32);
  const float inv = 1.f / lsum;
  const size_t rowoff = (size_t)(b * 2048 + q0 + la) * 1024 + h * 64 + hi * 4;
  #pragma unroll
  for (int dt = 0; dt < 2; ++dt) {
    #pragma unroll
    for (int r2 = 0; r2 < 4; ++r2) {
      u32x2 w;
      w[0] = cvt_pk_bf16(o[dt][r2 * 4 + 0] * inv, o[dt][r2 * 4 + 1] * inv);
      w[1] = cvt_pk_bf16(o[dt][r2 * 4 + 2] * inv, o[dt][r2 * 4 + 3] * inv);
      *(u32x2*)(Ao + rowoff + dt * 32 + r2 * 8) = w;
    }
  }
}

// ---------------- launch ----------------
extern "C" void kernel_launch(void* const* d_in, const int* in_sizes, int n_in,
                              void* d_out, int out_size, void* d_ws, size_t ws_size,
                              hipStream_t stream) {
  const float* x  = (const float*)d_in[0];
  const float* Wq = (const float*)d_in[1];
  const float* bq = (const float*)d_in[2];
  const float* Wk = (const float*)d_in[3];
  const float* bk = (const float*)d_in[4];
  const float* Wv = (const float*)d_in[5];
  const float* bv = (const float*)d_in[6];
  const float* Wo = (const float*)d_in[7];
  const float* bo = (const float*)d_in[8];
  float* out = (float*)d_out;

  char* ws = (char*)d_ws;
  size_t off = 0;
  auto alloc = [&](size_t bytes) -> void* {
    void* p = ws + off;
    off += (bytes + 255) & ~(size_t)255;
    return p;
  };
  unsigned short* xb    = (unsigned short*)alloc((size_t)8192 * 1024 * 2); // x bf16
  unsigned short* wqkvt = (unsigned short*)alloc((size_t)1152 * 1024 * 2); // [Wq;Wk;Wv]^T bf16
  unsigned short* wot   = (unsigned short*)alloc((size_t)1024 * 1024 * 2); // Wo^T bf16
  unsigned short* qb    = (unsigned short*)alloc((size_t)8192 * 1024 * 2); // Q (b,h,n,d) scaled
  unsigned short* kb    = (unsigned short*)alloc((size_t)8192 * 64 * 2);   // K (b,n,d)
  unsigned short* vt    = (unsigned short*)alloc((size_t)4 * 64 * 2048 * 2); // V^T permuted
  unsigned short* ao    = (unsigned short*)alloc((size_t)8192 * 1024 * 2); // attn out (b,n,1024)

  cvt_all_kernel<<<10368, 256, 0, stream>>>(x, xb, Wq, Wk, Wv, Wo, wqkvt, wot);
  gemm_kernel<0><<<dim3(64, 9), 256, 0, stream>>>(xb, wqkvt, bq, bk, bv, qb, kb, vt, 1024, 1152);
  attn_kernel<<<dim3(8, 64), 512, 0, stream>>>(qb, kb, vt, ao);
  gemm_kernel<2><<<dim3(64, 8), 256, 0, stream>>>(ao, wot, bo, nullptr, nullptr, out, nullptr, nullptr, 1024, 1024);
}